// Round 10
// baseline (239.485 us; speedup 1.0000x reference)
//
#include <hip/hip_runtime.h>
#include <math.h>

#define PATCH   32
#define NBINS   36
#define WPB     4           // waves (patches) per block
#define HW_N    (PATCH*PATCH)
#define TR      34          // padded rows: 0..33, interior 1..32
#define TC      34          // padded row stride (f32), cols 0..33

// Per-pixel pipeline in f32 (sector method, angle err ~1e-7); accumulation
// in f64 LDS atomics (order-independent => deterministic, flip-safe).
// w1 from the small residual s = dl*18/pi (f32 ulp ~3e-8 near 0).
// Sobel via rolling row-sums: lane owns column c=lane&31, half h=lane>>5;
// T(r)=a+2b+c_, D(r)=c_-a; gx=(D(r-1)+2D(r)+D(r+1))*wf, gy=(T(r+1)-T(r-1))*wf.
// LDS 19.9KB -> 8 blocks/CU (32 waves, 100% wave capacity).

__global__ __launch_bounds__(256, 8) void patch_dom_orient_kernel(
    const float* __restrict__ patch,
    const float* __restrict__ wk,
    const float* __restrict__ sw,
    float* __restrict__ out,
    int num_patches)
{
    __shared__ float  tile[WPB][TR][TC];   // 18.5 KB
    __shared__ double hist[WPB][NBINS];    // 1.15 KB
    __shared__ float2 cstab[37];           // 0.30 KB

    const int tid  = threadIdx.x;
    const int w    = tid >> 6;
    const int lane = tid & 63;
    const int p    = blockIdx.x * WPB + w;
    const int pc   = (p < num_patches) ? p : (num_patches - 1);

    // ---- zero histogram ----
    if (lane < NBINS) hist[w][lane] = 0.0;
    // ---- sector cos/sin table (per block) ----
    if (tid < 37) {
        double a = ((double)tid - 18.0) * 0.17453292519943295;  // pi/18
        cstab[tid] = make_float2((float)cos(a), (float)sin(a));
    }
    // ---- stage patch (f32) into padded tile interior ----
    const float4* pp4 = reinterpret_cast<const float4*>(patch + (size_t)pc * HW_N);
    #pragma unroll
    for (int i = 0; i < 4; ++i) {
        int idx4 = i * 64 + lane;            // 0..255
        float4 v = pp4[idx4];
        int flat = idx4 * 4;
        int row = flat >> 5;                 // 0..31
        int col = flat & 31;                 // 0,4,...,28
        float* dst = &tile[w][row + 1][col + 1];
        dst[0] = v.x; dst[1] = v.y; dst[2] = v.z; dst[3] = v.w;
    }
    // ---- edge duplication (clamp semantics); wave-synchronous ordering ----
    {
        int r = (lane >> 1) + 1;             // 1..32
        if (lane & 1) tile[w][r][33] = tile[w][r][32];
        else          tile[w][r][0]  = tile[w][r][1];
    }
    if (lane < 34) tile[w][0][lane]  = tile[w][1][lane];
    if (lane < 34) tile[w][33][lane] = tile[w][32][lane];
    __syncthreads();

    // ---- per-pixel: f32 rolling Sobel, sector angle, f64-atomic scatter ----
    {
        const int c  = lane & 31;            // owned column
        const int h  = lane >> 5;            // row-half
        const int r0 = h * 16;
        const float* rowp = &tile[w][r0][c];
        const float* wkp  = wk + r0 * 32 + c;
        double* hrep = &hist[w][0];

        float a0 = rowp[0], b0v = rowp[1], c0v = rowp[2];
        float Tm = fmaf(b0v, 2.0f, a0) + c0v;
        float Dm = c0v - a0;
        rowp += TC;
        float a1 = rowp[0], b1v = rowp[1], c1v = rowp[2];
        float T0 = fmaf(b1v, 2.0f, a1) + c1v;
        float D0 = c1v - a1;

        #pragma unroll
        for (int k = 0; k < 16; ++k) {
            rowp += TC;
            float ar = rowp[0], br = rowp[1], cr = rowp[2];
            float Tp = fmaf(br, 2.0f, ar) + cr;
            float Dp = cr - ar;

            float wf = wkp[k * 32] * 0.125f;
            float gx = (fmaf(D0, 2.0f, Dm) + Dp) * wf;
            float gy = (Tp - Tm) * wf;

            float xs = gx + 1e-18f;
            float m2 = fmaf(gx, gx, fmaf(gy, gy, 1e-18f));
            float r  = __builtin_amdgcn_rsqf(m2);   // ~1 ulp
            float mag = m2 * r;

            // sector estimate (octant-reduced deg-5 atan; err ~0.01 sector)
            float ax = fabsf(xs), ay = fabsf(gy);
            float mn = fminf(ax, ay), mx = fmaxf(ax, ay);
            mx = fmaxf(mx, 1e-30f);                 // guard 0/0 -> NaN
            float rq = mn * __builtin_amdgcn_rcpf(mx);
            float s2 = rq * rq;
            float at = rq * fmaf(s2, fmaf(s2, 0.0792f, -0.2885f), 0.9954f);
            if (ay > ax)    at = 1.5707963f - at;
            if (xs < 0.0f)  at = 3.1415927f - at;
            at = copysignf(at, gy);
            int n = (int)rintf(at * 5.7295780f);
            n = (n < -18) ? -18 : ((n > 18) ? 18 : n);

            // residual: rotate by -n*10deg; asin series through z^7
            float2 cs = cstab[n + 18];
            float yr = fmaf(gy, cs.x, -(xs * cs.y));
            float z  = yr * r;                      // sin(delta), |z|<=0.089
            float u  = z * z;
            float dl = z * fmaf(u, fmaf(u, fmaf(u, 0.044642857f, 0.075f),
                                        0.16666667f), 1.0f);
            float s  = dl * 5.7295780f;             // in (-0.51, 0.51)
            int neg  = (s < 0.0f) ? 1 : 0;
            float w1 = neg ? (s + 1.0f) : s;        // frac, ulp ~1e-7
            int bh   = n + 54 - neg;                // in [35, 72]
            int b0   = bh - ((bh >= 36) ? 36 : 0);
            b0       = b0 - ((b0 >= 36) ? 36 : 0);  // bh==72 -> bin 0
            int b1   = (b0 == 35) ? 0 : b0 + 1;

            float wo1 = w1 * mag;
            float wo0 = mag - wo1;
            atomicAdd(&hrep[b0], (double)wo0);
            atomicAdd(&hrep[b1], (double)wo1);

            Tm = T0; T0 = Tp; Dm = D0; D0 = Dp;
        }
    }
    __syncthreads();

    // ---- /HW, circular smooth (f64), value in registers ----
    double hs_val = -INFINITY;
    if (lane < NBINS) {
        int im1 = (lane == 0) ? NBINS - 1 : lane - 1;
        int ip1 = (lane == NBINS - 1) ? 0 : lane + 1;
        double hm = hist[w][im1];
        double h0 = hist[w][lane];
        double hp = hist[w][ip1];
        hs_val = ((double)sw[0] * hm + (double)sw[1] * h0 + (double)sw[2] * hp)
                 * (1.0 / 1024.0);
    }

    // ---- argmax over 36 bins (first-occurrence tie-break) ----
    double v  = hs_val;
    int    bi = (lane < NBINS) ? lane : 64;
    #pragma unroll
    for (int sft = 32; sft > 0; sft >>= 1) {
        double ov = __shfl_xor(v, sft, 64);
        int    oi = __shfl_xor(bi, sft, 64);
        if (ov > v || (ov == v && oi < bi)) { v = ov; bi = oi; }
    }

    // ---- neighbors via shuffle (bi is wave-uniform after butterfly) ----
    int ip = (bi == NBINS - 1) ? 0 : bi + 1;
    int im = (bi == 0) ? NBINS - 1 : bi - 1;
    double vp1 = __shfl(hs_val, ip, 64);
    double vm1 = __shfl(hs_val, im, 64);

    // ---- refinement + angle (lane 0 writes) ----
    if (lane == 0 && p < num_patches) {
        double refinement = ((vp1 - vm1) / 2.0) / (2.0 * v - (vp1 + vm1));
        double idx_ref = (double)bi + refinement;
        double angle = -((2.0 * M_PI * idx_ref) / 36.0 - M_PI);
        out[p] = (float)angle;
    }
}

extern "C" void kernel_launch(void* const* d_in, const int* in_sizes, int n_in,
                              void* d_out, int out_size, void* d_ws, size_t ws_size,
                              hipStream_t stream) {
    const float* patch = (const float*)d_in[0];
    const float* wk    = (const float*)d_in[1];
    const float* sw    = (const float*)d_in[2];
    float* out = (float*)d_out;

    int num_patches = in_sizes[0] / HW_N;          // 32768
    int blocks = (num_patches + WPB - 1) / WPB;    // 8192

    patch_dom_orient_kernel<<<blocks, 256, 0, stream>>>(patch, wk, sw, out, num_patches);
}

// Round 11
// 238.968 us; speedup vs baseline: 1.0022x; 1.0022x over previous
//
#include <hip/hip_runtime.h>
#include <math.h>

#define PATCH   32
#define NBINS   36
#define WPB     4           // waves (patches) per block
#define HW_N    (PATCH*PATCH)
#define TR      34          // padded rows: 0..33, interior 1..32
#define TC      34          // padded row stride (f32), cols 0..33

// Per-pixel pipeline in f32 (sector method, angle err ~1e-7); accumulation
// in f64 LDS atomics (order-independent => deterministic, flip-safe).
// NO barriers: each wave touches only tile[w]/hist[w]; LDS ops of a wave
// complete in program order (same property the edge-dup code has used since
// R4). cstab is written redundantly by every wave (identical values).
// Sobel via rolling row-sums: lane owns column c=lane&31, half h=lane>>5;
// T(r)=a+2b+c_, D(r)=c_-a; gx=(D(r-1)+2D(r)+D(r+1))*wf, gy=(T(r+1)-T(r-1))*wf.
// LDS 19.9KB -> 8 blocks/CU (32 waves).

__global__ __launch_bounds__(256, 8) void patch_dom_orient_kernel(
    const float* __restrict__ patch,
    const float* __restrict__ wk,
    const float* __restrict__ sw,
    float* __restrict__ out,
    int num_patches)
{
    __shared__ float  tile[WPB][TR][TC];   // 18.5 KB
    __shared__ double hist[WPB][NBINS];    // 1.15 KB
    __shared__ float2 cstab[37];           // 0.30 KB

    const int tid  = threadIdx.x;
    const int w    = tid >> 6;
    const int lane = tid & 63;
    const int p    = blockIdx.x * WPB + w;
    const int pc   = (p < num_patches) ? p : (num_patches - 1);

    // ---- zero histogram (own wave's) ----
    if (lane < NBINS) hist[w][lane] = 0.0;
    // ---- sector cos/sin table: every wave writes identical values ----
    if (lane < 37) {
        double a = ((double)lane - 18.0) * 0.17453292519943295;  // pi/18
        cstab[lane] = make_float2((float)cos(a), (float)sin(a));
    }
    // ---- stage patch (f32) into padded tile interior ----
    const float4* pp4 = reinterpret_cast<const float4*>(patch + (size_t)pc * HW_N);
    #pragma unroll
    for (int i = 0; i < 4; ++i) {
        int idx4 = i * 64 + lane;            // 0..255
        float4 v = pp4[idx4];
        int flat = idx4 * 4;
        int row = flat >> 5;                 // 0..31
        int col = flat & 31;                 // 0,4,...,28
        float* dst = &tile[w][row + 1][col + 1];
        dst[0] = v.x; dst[1] = v.y; dst[2] = v.z; dst[3] = v.w;
    }
    // ---- edge duplication (clamp semantics); wave-ordered LDS ----
    {
        int r = (lane >> 1) + 1;             // 1..32
        if (lane & 1) tile[w][r][33] = tile[w][r][32];
        else          tile[w][r][0]  = tile[w][r][1];
    }
    if (lane < 34) tile[w][0][lane]  = tile[w][1][lane];
    if (lane < 34) tile[w][33][lane] = tile[w][32][lane];

    // ---- per-pixel: f32 rolling Sobel, sector angle, f64-atomic scatter ----
    {
        const int c  = lane & 31;            // owned column
        const int h  = lane >> 5;            // row-half
        const int r0 = h * 16;
        const float* rowp = &tile[w][r0][c];
        const float* wkp  = wk + r0 * 32 + c;
        double* hrep = &hist[w][0];

        float a0 = rowp[0], b0v = rowp[1], c0v = rowp[2];
        float Tm = fmaf(b0v, 2.0f, a0) + c0v;
        float Dm = c0v - a0;
        rowp += TC;
        float a1 = rowp[0], b1v = rowp[1], c1v = rowp[2];
        float T0 = fmaf(b1v, 2.0f, a1) + c1v;
        float D0 = c1v - a1;

        #pragma unroll 4
        for (int k = 0; k < 16; ++k) {
            rowp += TC;
            float ar = rowp[0], br = rowp[1], cr = rowp[2];
            float Tp = fmaf(br, 2.0f, ar) + cr;
            float Dp = cr - ar;

            float wf = wkp[k * 32] * 0.125f;
            float gx = (fmaf(D0, 2.0f, Dm) + Dp) * wf;
            float gy = (Tp - Tm) * wf;

            float xs = gx + 1e-18f;
            float m2 = fmaf(gx, gx, fmaf(gy, gy, 1e-18f));
            float r  = __builtin_amdgcn_rsqf(m2);   // ~1 ulp
            float mag = m2 * r;

            // sector estimate (octant-reduced deg-3 atan; err ~0.005 rad =
            // 0.03 sector; asin series still converges to ~1e-11 at the
            // enlarged residual |z|<=0.093)
            float ax = fabsf(xs), ay = fabsf(gy);
            float mn = fminf(ax, ay), mx = fmaxf(ax, ay);
            mx = fmaxf(mx, 1e-30f);                 // guard 0/0 -> NaN
            float rq = mn * __builtin_amdgcn_rcpf(mx);
            float at = rq * fmaf(rq * rq, -0.1919f, 0.9724f);
            if (ay > ax)    at = 1.5707963f - at;
            if (xs < 0.0f)  at = 3.1415927f - at;
            at = copysignf(at, gy);
            // |at| <= pi+0.005 -> at*5.7296 in [-18.03,18.03] -> n in [-18,18]
            int n = (int)rintf(at * 5.7295780f);

            // residual: rotate by -n*10deg; asin series through z^7
            float2 cs = cstab[n + 18];
            float yr = fmaf(gy, cs.x, -(xs * cs.y));
            float z  = yr * r;                      // sin(delta)
            float u  = z * z;
            float dl = z * fmaf(u, fmaf(u, fmaf(u, 0.044642857f, 0.075f),
                                        0.16666667f), 1.0f);
            float s  = dl * 5.7295780f;             // in (-0.55, 0.55)
            int neg  = (s < 0.0f) ? 1 : 0;
            float w1 = neg ? (s + 1.0f) : s;        // frac, ulp ~1e-7
            int bh   = n + 54 - neg;                // in [35, 72]
            int b0   = bh - ((bh >= 36) ? 36 : 0);
            b0       = b0 - ((b0 >= 36) ? 36 : 0);  // bh==72 -> bin 0
            int b1   = (b0 == 35) ? 0 : b0 + 1;

            float wo1 = w1 * mag;
            float wo0 = mag - wo1;
            atomicAdd(&hrep[b0], (double)wo0);
            atomicAdd(&hrep[b1], (double)wo1);

            Tm = T0; T0 = Tp; Dm = D0; D0 = Dp;
        }
    }

    // ---- /HW, circular smooth (f64); wave-ordered after own atomics ----
    double hs_val = -INFINITY;
    if (lane < NBINS) {
        int im1 = (lane == 0) ? NBINS - 1 : lane - 1;
        int ip1 = (lane == NBINS - 1) ? 0 : lane + 1;
        double hm = hist[w][im1];
        double h0 = hist[w][lane];
        double hp = hist[w][ip1];
        hs_val = ((double)sw[0] * hm + (double)sw[1] * h0 + (double)sw[2] * hp)
                 * (1.0 / 1024.0);
    }

    // ---- argmax over 36 bins (first-occurrence tie-break) ----
    double v  = hs_val;
    int    bi = (lane < NBINS) ? lane : 64;
    #pragma unroll
    for (int sft = 32; sft > 0; sft >>= 1) {
        double ov = __shfl_xor(v, sft, 64);
        int    oi = __shfl_xor(bi, sft, 64);
        if (ov > v || (ov == v && oi < bi)) { v = ov; bi = oi; }
    }

    // ---- neighbors via shuffle (bi is wave-uniform after butterfly) ----
    int ip = (bi == NBINS - 1) ? 0 : bi + 1;
    int im = (bi == 0) ? NBINS - 1 : bi - 1;
    double vp1 = __shfl(hs_val, ip, 64);
    double vm1 = __shfl(hs_val, im, 64);

    // ---- refinement + angle (lane 0 writes) ----
    if (lane == 0 && p < num_patches) {
        double refinement = ((vp1 - vm1) / 2.0) / (2.0 * v - (vp1 + vm1));
        double idx_ref = (double)bi + refinement;
        double angle = -((2.0 * M_PI * idx_ref) / 36.0 - M_PI);
        out[p] = (float)angle;
    }
}

extern "C" void kernel_launch(void* const* d_in, const int* in_sizes, int n_in,
                              void* d_out, int out_size, void* d_ws, size_t ws_size,
                              hipStream_t stream) {
    const float* patch = (const float*)d_in[0];
    const float* wk    = (const float*)d_in[1];
    const float* sw    = (const float*)d_in[2];
    float* out = (float*)d_out;

    int num_patches = in_sizes[0] / HW_N;          // 32768
    int blocks = (num_patches + WPB - 1) / WPB;    // 8192

    patch_dom_orient_kernel<<<blocks, 256, 0, stream>>>(patch, wk, sw, out, num_patches);
}